// Round 1
// baseline (427.215 us; speedup 1.0000x reference)
//
#include <hip/hip_runtime.h>
#include <math.h>

// Problem constants
#define B_    8
#define N_    2000
#define ET_   2
#define L_    8
#define D_    64
#define NNZ_  32000
#define EN_   4000          // ET_*N_
#define LD_   512           // L_*D_
#define SEGS_ 16            // B_*ET_
#define SEGSTR_ 2001        // N_+1
#define TOTE_ 512000        // B_*ET_*NNZ_

// ---------------- CSR build ----------------
__global__ void hist_kernel(const int* __restrict__ rows, int* __restrict__ ptr) {
    int idx = blockIdx.x * 256 + threadIdx.x;          // < TOTE_
    int seg = idx / NNZ_;                              // b*2+t  (A arrays are [B,2,NNZ])
    int row = rows[idx];
    atomicAdd(&ptr[seg * SEGSTR_ + row + 1], 1);
}

__global__ void scan_kernel(int* __restrict__ ptr, int* __restrict__ cursor) {
    int seg = blockIdx.x;                              // 16 blocks
    int* p = ptr + seg * SEGSTR_;
    int* c = cursor + seg * SEGSTR_;
    __shared__ int totals[256];
    int t = threadIdx.x;
    int v[8];
    int run = 0;
    int base = t * 8;
#pragma unroll
    for (int k = 0; k < 8; ++k) {
        int i = base + k;
        int x = (i < SEGSTR_) ? p[i] : 0;
        run += x;
        v[k] = run;
    }
    totals[t] = run;
    __syncthreads();
    if (t == 0) {
        int r = 0;
        for (int i = 0; i < 256; ++i) { int tmp = totals[i]; totals[i] = r; r += tmp; }
    }
    __syncthreads();
    int off = totals[t];
#pragma unroll
    for (int k = 0; k < 8; ++k) {
        int i = base + k;
        if (i < SEGSTR_) {
            int val = off + v[k];
            p[i] = val;
            c[i] = val;
        }
    }
}

__global__ void fill_kernel(const int* __restrict__ rows, int* __restrict__ cursor,
                            int* __restrict__ perm) {
    int idx = blockIdx.x * 256 + threadIdx.x;          // < TOTE_
    int seg = idx / NNZ_;
    int e = idx - seg * NNZ_;
    int row = rows[idx];
    int pos = atomicAdd(&cursor[seg * SEGSTR_ + row], 1);
    perm[seg * NNZ_ + pos] = e;
}

// ---------------- SpMM gather: one wave per (seg,row) ----------------
__global__ __launch_bounds__(256) void gather_kernel(
    const float* __restrict__ state_in, const float* __restrict__ state_out,
    const float* __restrict__ vals, const int* __restrict__ cols,
    const int* __restrict__ ptr, const int* __restrict__ perm,
    float* __restrict__ a_buf) {
    int wid = (blockIdx.x << 2) + (threadIdx.x >> 6);  // < SEGS_*N_ = 32000
    int lane = threadIdx.x & 63;
    int seg = wid / N_;
    int row = wid - seg * N_;
    int b = seg >> 1, t = seg & 1;
    const float* st = t ? state_out : state_in;
    int s0 = ptr[seg * SEGSTR_ + row];
    int s1 = ptr[seg * SEGSTR_ + row + 1];
    float4 a0 = make_float4(0.f, 0.f, 0.f, 0.f);
    float4 a1 = make_float4(0.f, 0.f, 0.f, 0.f);
    for (int j = s0; j < s1; ++j) {
        int e = perm[seg * NNZ_ + j];
        float v = vals[seg * NNZ_ + e];
        int col = cols[seg * NNZ_ + e];
        const float* src = st + ((size_t)(b * EN_ + col)) * LD_ + lane * 8;
        float4 x0 = *(const float4*)src;
        float4 x1 = *(const float4*)(src + 4);
        a0.x += v * x0.x; a0.y += v * x0.y; a0.z += v * x0.z; a0.w += v * x0.w;
        a1.x += v * x1.x; a1.y += v * x1.y; a1.z += v * x1.z; a1.w += v * x1.w;
    }
    float* dst = a_buf + ((size_t)((t * B_ + b) * N_ + row)) * LD_ + lane * 8;
    *(float4*)dst = a0;
    *(float4*)(dst + 4) = a1;
}

// ---------------- GRU / 3x matvec kernel ----------------
// block = 256 threads = 4 waves; block handles 64 GEMM rows (wave: 16 rows).
// GEMM row r = (b*N+n)*L + l  -> all row-major arrays are contiguous in r.
__global__ __launch_bounds__(256) void gru_kernel(
    const float* __restrict__ a_buf, const float* __restrict__ state_cur,
    const float* __restrict__ Wr, const float* __restrict__ br,
    const float* __restrict__ Wz, const float* __restrict__ bz,
    const float* __restrict__ Wh, const float* __restrict__ bh,
    float* __restrict__ out) {
    __shared__ float ash[64][192];
    int tid = threadIdx.x;
    int wave = tid >> 6, lane = tid & 63;
    size_t R0 = (size_t)blockIdx.x * 64;

    // stage 64 rows x (a_in|a_out|cur) into LDS, fully coalesced
    const float4* sin  = (const float4*)(a_buf + R0 * 64);
    const float4* sout = (const float4*)(a_buf + (size_t)B_ * N_ * LD_ + R0 * 64);
    const float4* scur = (const float4*)(state_cur + R0 * 64);
    for (int i = tid; i < 1024; i += 256) {
        int row = i >> 4;
        int c = (i & 15) << 2;
        *(float4*)&ash[row][c]       = sin[i];
        *(float4*)&ash[row][64 + c]  = sout[i];
        *(float4*)&ash[row][128 + c] = scur[i];
    }
    __syncthreads();

    int r0 = wave * 16;
    float accR[16], accZ[16];
#pragma unroll
    for (int rr = 0; rr < 16; ++rr) { accR[rr] = 0.f; accZ[rr] = 0.f; }

    const float4* wr4 = (const float4*)(Wr + lane * 192);
    const float4* wz4 = (const float4*)(Wz + lane * 192);
    const float4* wh4 = (const float4*)(Wh + lane * 192);

    for (int k4 = 0; k4 < 48; ++k4) {
        float4 wr = wr4[k4];
        float4 wz = wz4[k4];
#pragma unroll
        for (int rr = 0; rr < 16; ++rr) {
            float4 a = *(const float4*)&ash[r0 + rr][k4 << 2];   // broadcast read
            accR[rr] += a.x * wr.x + a.y * wr.y + a.z * wr.z + a.w * wr.w;
            accZ[rr] += a.x * wz.x + a.y * wz.y + a.z * wz.z + a.w * wz.w;
        }
    }

    float brl = br[lane], bzl = bz[lane], bhl = bh[lane];
    float curreg[16];
#pragma unroll
    for (int rr = 0; rr < 16; ++rr) curreg[rr] = ash[r0 + rr][128 + lane];
    // r gate; overwrite cur segment of LDS with r*cur (joined vector)
#pragma unroll
    for (int rr = 0; rr < 16; ++rr) {
        float rg = 1.f / (1.f + __expf(-(accR[rr] + brl)));
        ash[r0 + rr][128 + lane] = rg * curreg[rr];
    }
    __syncthreads();   // cross-lane visibility of r*cur

    float accH[16];
#pragma unroll
    for (int rr = 0; rr < 16; ++rr) accH[rr] = 0.f;
    for (int k4 = 0; k4 < 48; ++k4) {
        float4 wh = wh4[k4];
#pragma unroll
        for (int rr = 0; rr < 16; ++rr) {
            float4 a = *(const float4*)&ash[r0 + rr][k4 << 2];
            accH[rr] += a.x * wh.x + a.y * wh.y + a.z * wh.z + a.w * wh.w;
        }
    }

    float* outp = out + R0 * 64;
#pragma unroll
    for (int rr = 0; rr < 16; ++rr) {
        float z = 1.f / (1.f + __expf(-(accZ[rr] + bzl)));
        float hh = tanhf(accH[rr] + bhl);
        outp[(r0 + rr) * 64 + lane] = (1.f - z) * curreg[rr] + z * hh;
    }
}

extern "C" void kernel_launch(void* const* d_in, const int* in_sizes, int n_in,
                              void* d_out, int out_size, void* d_ws, size_t ws_size,
                              hipStream_t stream) {
    const float* state_in  = (const float*)d_in[0];
    const float* state_out = (const float*)d_in[1];
    const float* state_cur = (const float*)d_in[2];
    const float* A_vals    = (const float*)d_in[3];
    const int*   A_rows    = (const int*)d_in[4];
    const int*   A_cols    = (const int*)d_in[5];
    const float* W_r = (const float*)d_in[6];
    const float* b_r = (const float*)d_in[7];
    const float* W_z = (const float*)d_in[8];
    const float* b_z = (const float*)d_in[9];
    const float* W_h = (const float*)d_in[10];
    const float* b_h = (const float*)d_in[11];
    float* out = (float*)d_out;

    float* ws = (float*)d_ws;
    float* a_buf  = ws;                                  // 2*B*N*LD = 16,384,000 f
    int*   ptr    = (int*)(ws + 16384000);               // 16*2001 = 32,016 i
    int*   cursor = ptr + 32016;                         // 32,016 i
    int*   perm   = cursor + 32016;                      // 512,000 i

    hipMemsetAsync(ptr, 0, 32016 * sizeof(int), stream);
    hist_kernel<<<TOTE_ / 256, 256, 0, stream>>>(A_rows, ptr);
    scan_kernel<<<SEGS_, 256, 0, stream>>>(ptr, cursor);
    fill_kernel<<<TOTE_ / 256, 256, 0, stream>>>(A_rows, cursor, perm);
    gather_kernel<<<(SEGS_ * N_) / 4, 256, 0, stream>>>(state_in, state_out, A_vals, A_cols,
                                                        ptr, perm, a_buf);
    gru_kernel<<<(B_ * N_ * L_) / 64, 256, 0, stream>>>(a_buf, state_cur,
                                                        W_r, b_r, W_z, b_z, W_h, b_h, out);
}

// Round 2
// 285.160 us; speedup vs baseline: 1.4982x; 1.4982x over previous
//
#include <hip/hip_runtime.h>
#include <math.h>

// Problem constants
#define B_    8
#define N_    2000
#define ET_   2
#define L_    8
#define D_    64
#define NNZ_  32000
#define EN_   4000          // ET_*N_
#define LD_   512           // L_*D_
#define SEGS_ 16            // B_*ET_
#define SEGSTR_ 2001        // N_+1
#define TOTE_ 512000        // B_*ET_*NNZ_
#define ROWS_ 128000        // B_*N_*L_  (GEMM rows)

typedef __attribute__((ext_vector_type(8))) short short8;
typedef __attribute__((ext_vector_type(4))) float f32x4;

// round-to-nearest-even f32 -> bf16 bits
__device__ __forceinline__ ushort bf(float x) {
    unsigned u = __float_as_uint(x);
    unsigned r = (u + 0x7FFFu + ((u >> 16) & 1u)) >> 16;
    return (ushort)r;
}

// ---------------- CSR build ----------------
__global__ void hist_kernel(const int* __restrict__ rows, int* __restrict__ ptr) {
    int idx = blockIdx.x * 256 + threadIdx.x;          // < TOTE_
    int seg = idx / NNZ_;                              // b*2+t  (A arrays are [B,2,NNZ])
    int row = rows[idx];
    atomicAdd(&ptr[seg * SEGSTR_ + row + 1], 1);
}

__global__ void scan_kernel(int* __restrict__ ptr, int* __restrict__ cursor) {
    int seg = blockIdx.x;                              // 16 blocks
    int* p = ptr + seg * SEGSTR_;
    int* c = cursor + seg * SEGSTR_;
    __shared__ int totals[256];
    int t = threadIdx.x;
    int v[8];
    int run = 0;
    int base = t * 8;
#pragma unroll
    for (int k = 0; k < 8; ++k) {
        int i = base + k;
        int x = (i < SEGSTR_) ? p[i] : 0;
        run += x;
        v[k] = run;
    }
    totals[t] = run;
    __syncthreads();
    if (t == 0) {
        int r = 0;
        for (int i = 0; i < 256; ++i) { int tmp = totals[i]; totals[i] = r; r += tmp; }
    }
    __syncthreads();
    int off = totals[t];
#pragma unroll
    for (int k = 0; k < 8; ++k) {
        int i = base + k;
        if (i < SEGSTR_) {
            int val = off + v[k];
            p[i] = val;
            c[i] = val;
        }
    }
}

__global__ void fill_kernel(const int* __restrict__ rows, int* __restrict__ cursor,
                            int* __restrict__ perm) {
    int idx = blockIdx.x * 256 + threadIdx.x;          // < TOTE_
    int seg = idx / NNZ_;
    int e = idx - seg * NNZ_;
    int row = rows[idx];
    int pos = atomicAdd(&cursor[seg * SEGSTR_ + row], 1);
    perm[seg * NNZ_ + pos] = e;
}

// ---------------- weight prep: f32 [64,192]x3 -> bf16 [192,192] ----------------
// Wbf row o: o<64 -> Wr[o]; o<128 -> Wz[o-64]; else Wh[o-128]
__global__ void wprep_kernel(const float* __restrict__ Wr, const float* __restrict__ Wz,
                             const float* __restrict__ Wh, ushort* __restrict__ Wbf) {
    int cid = blockIdx.x * 256 + threadIdx.x;          // < 4608 chunks of 8
    if (cid >= 4608) return;
    int row = cid / 24, c0 = (cid % 24) * 8;
    const float* src = (row < 64) ? (Wr + row * 192)
                     : (row < 128) ? (Wz + (row - 64) * 192)
                                   : (Wh + (row - 128) * 192);
    float4 v0 = *(const float4*)(src + c0);
    float4 v1 = *(const float4*)(src + c0 + 4);
    union { ushort u[8]; uint4 v; } pk;
    pk.u[0] = bf(v0.x); pk.u[1] = bf(v0.y); pk.u[2] = bf(v0.z); pk.u[3] = bf(v0.w);
    pk.u[4] = bf(v1.x); pk.u[5] = bf(v1.y); pk.u[6] = bf(v1.z); pk.u[7] = bf(v1.w);
    *(uint4*)(Wbf + row * 192 + c0) = pk.v;
}

// ---------------- SpMM gather: one wave per (seg,row), bf16 output ----------------
__global__ __launch_bounds__(256) void gather_kernel(
    const float* __restrict__ state_in, const float* __restrict__ state_out,
    const float* __restrict__ vals, const int* __restrict__ cols,
    const int* __restrict__ ptr, const int* __restrict__ perm,
    ushort* __restrict__ abuf) {
    int wid = (blockIdx.x << 2) + (threadIdx.x >> 6);  // < SEGS_*N_ = 32000
    int lane = threadIdx.x & 63;
    int seg = wid / N_;
    int row = wid - seg * N_;
    int b = seg >> 1, t = seg & 1;
    const float* st = t ? state_out : state_in;
    int s0 = ptr[seg * SEGSTR_ + row];
    int s1 = ptr[seg * SEGSTR_ + row + 1];
    float4 a0 = make_float4(0.f, 0.f, 0.f, 0.f);
    float4 a1 = make_float4(0.f, 0.f, 0.f, 0.f);
    for (int j = s0; j < s1; ++j) {
        int e = perm[seg * NNZ_ + j];
        float v = vals[seg * NNZ_ + e];
        int col = cols[seg * NNZ_ + e];
        const float* src = st + ((size_t)(b * EN_ + col)) * LD_ + lane * 8;
        float4 x0 = *(const float4*)src;
        float4 x1 = *(const float4*)(src + 4);
        a0.x += v * x0.x; a0.y += v * x0.y; a0.z += v * x0.z; a0.w += v * x0.w;
        a1.x += v * x1.x; a1.y += v * x1.y; a1.z += v * x1.z; a1.w += v * x1.w;
    }
    union { ushort u[8]; uint4 v; } pk;
    pk.u[0] = bf(a0.x); pk.u[1] = bf(a0.y); pk.u[2] = bf(a0.z); pk.u[3] = bf(a0.w);
    pk.u[4] = bf(a1.x); pk.u[5] = bf(a1.y); pk.u[6] = bf(a1.z); pk.u[7] = bf(a1.w);
    ushort* dst = abuf + ((size_t)((t * B_ + b) * N_ + row)) * LD_ + lane * 8;
    *(uint4*)dst = pk.v;
}

// ---------------- GRU via MFMA bf16 ----------------
// Block: 256 thr = 4 waves, 64 GEMM rows. Wave: 16 rows (one 16-row MFMA tile).
// A = [a_in | a_out | cur] in LDS bf16 [64][200] (pad -> 2-way conflicts only).
// RZ pass: 8 col-tiles (cols 0-63 = r, 64-127 = z); H pass: 4 col-tiles.
// Fragment k-mapping: same permutation used for A and B -> contraction correct
// independent of the hardware's internal k layout. C/D: col=lane&15, row=(lane>>4)*4+reg.
__global__ __launch_bounds__(256) void gru_kernel(
    const ushort* __restrict__ abuf, const float* __restrict__ state_cur,
    const ushort* __restrict__ Wbf,
    const float* __restrict__ br, const float* __restrict__ bz, const float* __restrict__ bh,
    float* __restrict__ out) {
    __shared__ ushort ash[64][200];
    int tid = threadIdx.x;
    int wave = tid >> 6, lane = tid & 63;
    int R0 = blockIdx.x * 64;

    // stage 64 rows: a_in (cols 0-63), a_out (64-127) bf16 direct; cur (128-191) f32->bf16
    {
        const uint4* pin  = (const uint4*)(abuf + (size_t)R0 * 64);
        const uint4* pout = (const uint4*)(abuf + (size_t)ROWS_ * 64 + (size_t)R0 * 64);
        for (int i = tid; i < 512; i += 256) {
            int row = i >> 3, c = (i & 7) * 8;
            *(uint4*)&ash[row][c]      = pin[i];
            *(uint4*)&ash[row][64 + c] = pout[i];
        }
        for (int i = tid; i < 1024; i += 256) {
            int row = i >> 4, c = (i & 15) * 4;
            float4 v = *(const float4*)(state_cur + (size_t)(R0 + row) * 64 + c);
            ushort4 h;
            h.x = bf(v.x); h.y = bf(v.y); h.z = bf(v.z); h.w = bf(v.w);
            *(ushort4*)&ash[row][128 + c] = h;
        }
    }
    __syncthreads();

    int g = lane >> 4;                 // k-group 0..3
    int oc = lane & 15;                // output col within tile / A row within tile
    int arow = wave * 16 + oc;         // this lane's A row for frag loads

    short8 afr[6];
#pragma unroll
    for (int s = 0; s < 6; ++s)
        afr[s] = *(const short8*)&ash[arow][s * 32 + g * 8];

    f32x4 accRZ[8];
#pragma unroll
    for (int ct = 0; ct < 8; ++ct) accRZ[ct] = (f32x4)(0.f);
#pragma unroll
    for (int ct = 0; ct < 8; ++ct) {
        const ushort* wp = Wbf + (ct * 16 + oc) * 192 + g * 8;
#pragma unroll
        for (int s = 0; s < 6; ++s) {
            short8 bfr = *(const short8*)(wp + s * 32);
            accRZ[ct] = __builtin_amdgcn_mfma_f32_16x16x32_bf16(afr[s], bfr, accRZ[ct], 0, 0, 0);
        }
    }

    // epilogue RZ: r = sigmoid(.); write r*cur (bf16) into LDS cols 128-191
    int rbase = wave * 16 + g * 4;     // C/D row for reg q: rbase+q
    float brl[4], bzl[4], bhl[4];
    float curv[4][4];
#pragma unroll
    for (int ct = 0; ct < 4; ++ct) {
        brl[ct] = br[ct * 16 + oc];
        bzl[ct] = bz[ct * 16 + oc];
        bhl[ct] = bh[ct * 16 + oc];
    }
#pragma unroll
    for (int ct = 0; ct < 4; ++ct) {
#pragma unroll
        for (int q = 0; q < 4; ++q) {
            curv[ct][q] = state_cur[(size_t)(R0 + rbase + q) * 64 + ct * 16 + oc];
            float rg = 1.f / (1.f + __expf(-(accRZ[ct][q] + brl[ct])));
            ash[rbase + q][128 + ct * 16 + oc] = bf(rg * curv[ct][q]);
        }
    }
    __syncthreads();

    // H pass: k-blocks 0-3 unchanged (a_in/a_out), reload 4-5 (r*cur)
    afr[4] = *(const short8*)&ash[arow][4 * 32 + g * 8];
    afr[5] = *(const short8*)&ash[arow][5 * 32 + g * 8];
    f32x4 accH[4];
#pragma unroll
    for (int ct = 0; ct < 4; ++ct) accH[ct] = (f32x4)(0.f);
#pragma unroll
    for (int ct = 0; ct < 4; ++ct) {
        const ushort* wp = Wbf + (128 + ct * 16 + oc) * 192 + g * 8;
#pragma unroll
        for (int s = 0; s < 6; ++s) {
            short8 bfr = *(const short8*)(wp + s * 32);
            accH[ct] = __builtin_amdgcn_mfma_f32_16x16x32_bf16(afr[s], bfr, accH[ct], 0, 0, 0);
        }
    }

    // final: out = (1-z)*cur + z*tanh(h)
#pragma unroll
    for (int ct = 0; ct < 4; ++ct) {
#pragma unroll
        for (int q = 0; q < 4; ++q) {
            float z = 1.f / (1.f + __expf(-(accRZ[4 + ct][q] + bzl[ct])));
            float hh = tanhf(accH[ct][q] + bhl[ct]);
            out[(size_t)(R0 + rbase + q) * 64 + ct * 16 + oc] =
                (1.f - z) * curv[ct][q] + z * hh;
        }
    }
}

extern "C" void kernel_launch(void* const* d_in, const int* in_sizes, int n_in,
                              void* d_out, int out_size, void* d_ws, size_t ws_size,
                              hipStream_t stream) {
    const float* state_in  = (const float*)d_in[0];
    const float* state_out = (const float*)d_in[1];
    const float* state_cur = (const float*)d_in[2];
    const float* A_vals    = (const float*)d_in[3];
    const int*   A_rows    = (const int*)d_in[4];
    const int*   A_cols    = (const int*)d_in[5];
    const float* W_r = (const float*)d_in[6];
    const float* b_r = (const float*)d_in[7];
    const float* W_z = (const float*)d_in[8];
    const float* b_z = (const float*)d_in[9];
    const float* W_h = (const float*)d_in[10];
    const float* b_h = (const float*)d_in[11];
    float* out = (float*)d_out;

    // workspace layout (bytes): abuf bf16 [2*ROWS_*64] | Wbf bf16 [192*192] | ints
    ushort* abuf = (ushort*)d_ws;                        // 16,384,000 ushorts
    ushort* Wbf  = abuf + (size_t)2 * ROWS_ * 64;        // 36,864 ushorts
    int* ptr     = (int*)(Wbf + 36864);                  // 16*2001
    int* cursor  = ptr + 32016;
    int* perm    = cursor + 32016;                       // 512,000

    hipMemsetAsync(ptr, 0, 32016 * sizeof(int), stream);
    wprep_kernel<<<18, 256, 0, stream>>>(W_r, W_z, W_h, Wbf);
    hist_kernel<<<TOTE_ / 256, 256, 0, stream>>>(A_rows, ptr);
    scan_kernel<<<SEGS_, 256, 0, stream>>>(ptr, cursor);
    fill_kernel<<<TOTE_ / 256, 256, 0, stream>>>(A_rows, cursor, perm);
    gather_kernel<<<(SEGS_ * N_) / 4, 256, 0, stream>>>(state_in, state_out, A_vals, A_cols,
                                                        ptr, perm, abuf);
    gru_kernel<<<ROWS_ / 64, 256, 0, stream>>>(abuf, state_cur, Wbf,
                                               b_r, b_z, b_h, out);
}

// Round 3
// 234.618 us; speedup vs baseline: 1.8209x; 1.2154x over previous
//
#include <hip/hip_runtime.h>
#include <math.h>

// Problem constants
#define B_    8
#define N_    2000
#define ET_   2
#define L_    8
#define D_    64
#define NNZ_  32000
#define EN_   4000          // ET_*N_
#define LD_   512           // L_*D_
#define SEGS_ 16            // B_*ET_
#define SEGSTR_ 2001        // N_+1
#define TOTE_ 512000        // B_*ET_*NNZ_
#define ROWS_ 128000        // B_*N_*L_  (GEMM rows)
#define STHALF_ 16384000    // B_*EN_*LD_ elements per state tensor

typedef __attribute__((ext_vector_type(8))) short short8;
typedef __attribute__((ext_vector_type(4))) float f32x4;

// round-to-nearest-even f32 -> bf16 bits
__device__ __forceinline__ ushort bf(float x) {
    unsigned u = __float_as_uint(x);
    unsigned r = (u + 0x7FFFu + ((u >> 16) & 1u)) >> 16;
    return (ushort)r;
}

// ---------------- state f32 -> bf16 conversion (streaming) ----------------
__global__ __launch_bounds__(256) void conv_kernel(const float* __restrict__ s_in,
                                                   const float* __restrict__ s_out,
                                                   ushort* __restrict__ st_bf) {
    int cid = blockIdx.x * 256 + threadIdx.x;          // < 4,096,000 chunks of 8
    size_t idx = (size_t)cid * 8;
    const float* src;
    if (idx < (size_t)STHALF_) src = s_in + idx;
    else                       src = s_out + (idx - STHALF_);
    float4 v0 = *(const float4*)src;
    float4 v1 = *(const float4*)(src + 4);
    union { ushort u[8]; uint4 v; } pk;
    pk.u[0] = bf(v0.x); pk.u[1] = bf(v0.y); pk.u[2] = bf(v0.z); pk.u[3] = bf(v0.w);
    pk.u[4] = bf(v1.x); pk.u[5] = bf(v1.y); pk.u[6] = bf(v1.z); pk.u[7] = bf(v1.w);
    *(uint4*)(st_bf + idx) = pk.v;
}

// ---------------- CSR build ----------------
__global__ void hist_kernel(const int* __restrict__ rows, int* __restrict__ ptr) {
    int idx = blockIdx.x * 256 + threadIdx.x;          // < TOTE_
    int seg = idx / NNZ_;                              // b*2+t  (A arrays are [B,2,NNZ])
    int row = rows[idx];
    atomicAdd(&ptr[seg * SEGSTR_ + row + 1], 1);
}

__global__ void scan_kernel(int* __restrict__ ptr, int* __restrict__ cursor) {
    int seg = blockIdx.x;                              // 16 blocks
    int* p = ptr + seg * SEGSTR_;
    int* c = cursor + seg * SEGSTR_;
    __shared__ int totals[256];
    int t = threadIdx.x;
    int v[8];
    int run = 0;
    int base = t * 8;
#pragma unroll
    for (int k = 0; k < 8; ++k) {
        int i = base + k;
        int x = (i < SEGSTR_) ? p[i] : 0;
        run += x;
        v[k] = run;
    }
    totals[t] = run;
    __syncthreads();
    if (t == 0) {
        int r = 0;
        for (int i = 0; i < 256; ++i) { int tmp = totals[i]; totals[i] = r; r += tmp; }
    }
    __syncthreads();
    int off = totals[t];
#pragma unroll
    for (int k = 0; k < 8; ++k) {
        int i = base + k;
        if (i < SEGSTR_) {
            int val = off + v[k];
            p[i] = val;
            c[i] = val;
        }
    }
}

// permute vals/cols directly into CSR order (no perm indirection later)
__global__ void fill_kernel(const int* __restrict__ rows, const float* __restrict__ vals,
                            const int* __restrict__ cols, int* __restrict__ cursor,
                            float* __restrict__ vals_s, int* __restrict__ cols_s) {
    int idx = blockIdx.x * 256 + threadIdx.x;          // < TOTE_
    int seg = idx / NNZ_;
    int row = rows[idx];
    int pos = atomicAdd(&cursor[seg * SEGSTR_ + row], 1);
    vals_s[seg * NNZ_ + pos] = vals[idx];
    cols_s[seg * NNZ_ + pos] = cols[idx];
}

// ---------------- SpMM gather (bf16 states): one wave per (seg,row) ----------------
// XCD-pinned: blockIdx.x & 7 selects XCD (round-robin dispatch); each XCD owns 2 segs,
// so its L2 sees only ~4.1 MB of bf16 state slab with ~8x reuse.
__global__ __launch_bounds__(256) void gather_bf_kernel(
    const ushort* __restrict__ st_bf, const float* __restrict__ vals_s,
    const int* __restrict__ cols_s, const int* __restrict__ ptr,
    ushort* __restrict__ abuf) {
    int xcd = blockIdx.x & 7;
    int s = blockIdx.x >> 3;                           // 0..999
    int half = (s >= 500) ? 1 : 0;
    int seg = xcd * 2 + half;
    int row = (s - half * 500) * 4 + (threadIdx.x >> 6);
    int lane = threadIdx.x & 63;
    int b = seg >> 1, t = seg & 1;
    const ushort* stp = st_bf + (size_t)t * STHALF_ + (size_t)b * (EN_ * LD_) + lane * 8;
    int s0 = ptr[seg * SEGSTR_ + row];
    int s1 = ptr[seg * SEGSTR_ + row + 1];
    int base = seg * NNZ_;
    float acc[8];
#pragma unroll
    for (int k = 0; k < 8; ++k) acc[k] = 0.f;
    for (int j = s0; j < s1; ++j) {
        float v = vals_s[base + j];
        int col = cols_s[base + j];
        uint4 x = *(const uint4*)(stp + (size_t)col * LD_);
        uint xs[4] = {x.x, x.y, x.z, x.w};
#pragma unroll
        for (int k = 0; k < 4; ++k) {
            float lo = __uint_as_float(xs[k] << 16);
            float hi = __uint_as_float(xs[k] & 0xFFFF0000u);
            acc[2 * k]     += v * lo;
            acc[2 * k + 1] += v * hi;
        }
    }
    union { ushort u[8]; uint4 v; } pk;
#pragma unroll
    for (int k = 0; k < 8; ++k) pk.u[k] = bf(acc[k]);
    ushort* dst = abuf + ((size_t)((t * B_ + b) * N_ + row)) * LD_ + lane * 8;
    *(uint4*)dst = pk.v;
}

// fallback (f32 states) if ws too small for bf16 copies
__global__ __launch_bounds__(256) void gather_f32_kernel(
    const float* __restrict__ state_in, const float* __restrict__ state_out,
    const float* __restrict__ vals_s, const int* __restrict__ cols_s,
    const int* __restrict__ ptr, ushort* __restrict__ abuf) {
    int xcd = blockIdx.x & 7;
    int s = blockIdx.x >> 3;
    int half = (s >= 500) ? 1 : 0;
    int seg = xcd * 2 + half;
    int row = (s - half * 500) * 4 + (threadIdx.x >> 6);
    int lane = threadIdx.x & 63;
    int b = seg >> 1, t = seg & 1;
    const float* st = (t ? state_out : state_in) + (size_t)b * (EN_ * LD_) + lane * 8;
    int s0 = ptr[seg * SEGSTR_ + row];
    int s1 = ptr[seg * SEGSTR_ + row + 1];
    int base = seg * NNZ_;
    float4 a0 = make_float4(0.f, 0.f, 0.f, 0.f);
    float4 a1 = make_float4(0.f, 0.f, 0.f, 0.f);
    for (int j = s0; j < s1; ++j) {
        float v = vals_s[base + j];
        int col = cols_s[base + j];
        const float* src = st + (size_t)col * LD_;
        float4 x0 = *(const float4*)src;
        float4 x1 = *(const float4*)(src + 4);
        a0.x += v * x0.x; a0.y += v * x0.y; a0.z += v * x0.z; a0.w += v * x0.w;
        a1.x += v * x1.x; a1.y += v * x1.y; a1.z += v * x1.z; a1.w += v * x1.w;
    }
    union { ushort u[8]; uint4 v; } pk;
    pk.u[0] = bf(a0.x); pk.u[1] = bf(a0.y); pk.u[2] = bf(a0.z); pk.u[3] = bf(a0.w);
    pk.u[4] = bf(a1.x); pk.u[5] = bf(a1.y); pk.u[6] = bf(a1.z); pk.u[7] = bf(a1.w);
    ushort* dst = abuf + ((size_t)((t * B_ + b) * N_ + row)) * LD_ + lane * 8;
    *(uint4*)dst = pk.v;
}

// ---------------- weight prep: f32 [64,192]x3 -> bf16 [192,192] ----------------
__global__ void wprep_kernel(const float* __restrict__ Wr, const float* __restrict__ Wz,
                             const float* __restrict__ Wh, ushort* __restrict__ Wbf) {
    int cid = blockIdx.x * 256 + threadIdx.x;          // < 4608 chunks of 8
    if (cid >= 4608) return;
    int row = cid / 24, c0 = (cid % 24) * 8;
    const float* src = (row < 64) ? (Wr + row * 192)
                     : (row < 128) ? (Wz + (row - 64) * 192)
                                   : (Wh + (row - 128) * 192);
    float4 v0 = *(const float4*)(src + c0);
    float4 v1 = *(const float4*)(src + c0 + 4);
    union { ushort u[8]; uint4 v; } pk;
    pk.u[0] = bf(v0.x); pk.u[1] = bf(v0.y); pk.u[2] = bf(v0.z); pk.u[3] = bf(v0.w);
    pk.u[4] = bf(v1.x); pk.u[5] = bf(v1.y); pk.u[6] = bf(v1.z); pk.u[7] = bf(v1.w);
    *(uint4*)(Wbf + row * 192 + c0) = pk.v;
}

// ---------------- GRU via MFMA bf16 ----------------
__global__ __launch_bounds__(256) void gru_kernel(
    const ushort* __restrict__ abuf, const float* __restrict__ state_cur,
    const ushort* __restrict__ Wbf,
    const float* __restrict__ br, const float* __restrict__ bz, const float* __restrict__ bh,
    float* __restrict__ out) {
    __shared__ ushort ash[64][200];
    int tid = threadIdx.x;
    int wave = tid >> 6, lane = tid & 63;
    int R0 = blockIdx.x * 64;

    {
        const uint4* pin  = (const uint4*)(abuf + (size_t)R0 * 64);
        const uint4* pout = (const uint4*)(abuf + (size_t)ROWS_ * 64 + (size_t)R0 * 64);
        for (int i = tid; i < 512; i += 256) {
            int row = i >> 3, c = (i & 7) * 8;
            *(uint4*)&ash[row][c]      = pin[i];
            *(uint4*)&ash[row][64 + c] = pout[i];
        }
        for (int i = tid; i < 1024; i += 256) {
            int row = i >> 4, c = (i & 15) * 4;
            float4 v = *(const float4*)(state_cur + (size_t)(R0 + row) * 64 + c);
            ushort4 h;
            h.x = bf(v.x); h.y = bf(v.y); h.z = bf(v.z); h.w = bf(v.w);
            *(ushort4*)&ash[row][128 + c] = h;
        }
    }
    __syncthreads();

    int g = lane >> 4;                 // k-group 0..3
    int oc = lane & 15;                // output col within tile / A row within tile
    int arow = wave * 16 + oc;

    short8 afr[6];
#pragma unroll
    for (int s = 0; s < 6; ++s)
        afr[s] = *(const short8*)&ash[arow][s * 32 + g * 8];

    f32x4 accRZ[8];
#pragma unroll
    for (int ct = 0; ct < 8; ++ct) accRZ[ct] = (f32x4)(0.f);
#pragma unroll
    for (int ct = 0; ct < 8; ++ct) {
        const ushort* wp = Wbf + (ct * 16 + oc) * 192 + g * 8;
#pragma unroll
        for (int s = 0; s < 6; ++s) {
            short8 bfr = *(const short8*)(wp + s * 32);
            accRZ[ct] = __builtin_amdgcn_mfma_f32_16x16x32_bf16(afr[s], bfr, accRZ[ct], 0, 0, 0);
        }
    }

    int rbase = wave * 16 + g * 4;
    float brl[4], bzl[4], bhl[4];
    float curv[4][4];
#pragma unroll
    for (int ct = 0; ct < 4; ++ct) {
        brl[ct] = br[ct * 16 + oc];
        bzl[ct] = bz[ct * 16 + oc];
        bhl[ct] = bh[ct * 16 + oc];
    }
#pragma unroll
    for (int ct = 0; ct < 4; ++ct) {
#pragma unroll
        for (int q = 0; q < 4; ++q) {
            curv[ct][q] = state_cur[(size_t)(R0 + rbase + q) * 64 + ct * 16 + oc];
            float rg = 1.f / (1.f + __expf(-(accRZ[ct][q] + brl[ct])));
            ash[rbase + q][128 + ct * 16 + oc] = bf(rg * curv[ct][q]);
        }
    }
    __syncthreads();

    afr[4] = *(const short8*)&ash[arow][4 * 32 + g * 8];
    afr[5] = *(const short8*)&ash[arow][5 * 32 + g * 8];
    f32x4 accH[4];
#pragma unroll
    for (int ct = 0; ct < 4; ++ct) accH[ct] = (f32x4)(0.f);
#pragma unroll
    for (int ct = 0; ct < 4; ++ct) {
        const ushort* wp = Wbf + (128 + ct * 16 + oc) * 192 + g * 8;
#pragma unroll
        for (int s = 0; s < 6; ++s) {
            short8 bfr = *(const short8*)(wp + s * 32);
            accH[ct] = __builtin_amdgcn_mfma_f32_16x16x32_bf16(afr[s], bfr, accH[ct], 0, 0, 0);
        }
    }

#pragma unroll
    for (int ct = 0; ct < 4; ++ct) {
#pragma unroll
        for (int q = 0; q < 4; ++q) {
            float z = 1.f / (1.f + __expf(-(accRZ[4 + ct][q] + bzl[ct])));
            float hh = tanhf(accH[ct][q] + bhl[ct]);
            out[(size_t)(R0 + rbase + q) * 64 + ct * 16 + oc] =
                (1.f - z) * curv[ct][q] + z * hh;
        }
    }
}

extern "C" void kernel_launch(void* const* d_in, const int* in_sizes, int n_in,
                              void* d_out, int out_size, void* d_ws, size_t ws_size,
                              hipStream_t stream) {
    const float* state_in  = (const float*)d_in[0];
    const float* state_out = (const float*)d_in[1];
    const float* state_cur = (const float*)d_in[2];
    const float* A_vals    = (const float*)d_in[3];
    const int*   A_rows    = (const int*)d_in[4];
    const int*   A_cols    = (const int*)d_in[5];
    const float* W_r = (const float*)d_in[6];
    const float* b_r = (const float*)d_in[7];
    const float* W_z = (const float*)d_in[8];
    const float* b_z = (const float*)d_in[9];
    const float* W_h = (const float*)d_in[10];
    const float* b_h = (const float*)d_in[11];
    float* out = (float*)d_out;

    // workspace layout
    char* p = (char*)d_ws;
    ushort* abuf = (ushort*)p;            p += (size_t)2 * ROWS_ * 64 * 2;   // 32,768,000 B
    ushort* Wbf  = (ushort*)p;            p += 36864 * 2;                    //     73,728 B
    int* ptr     = (int*)p;               p += 32016 * 4;                    //    128,064 B
    int* cursor  = (int*)p;               p += 32016 * 4;
    float* vals_s = (float*)p;            p += (size_t)SEGS_ * NNZ_ * 4;     //  2,048,000 B
    int* cols_s   = (int*)p;              p += (size_t)SEGS_ * NNZ_ * 4;
    ushort* st_bf = (ushort*)p;           p += (size_t)2 * STHALF_ * 2;      // 65,536,000 B
    bool bf16path = (size_t)(p - (char*)d_ws) <= ws_size;

    hipMemsetAsync(ptr, 0, 32016 * sizeof(int), stream);
    wprep_kernel<<<18, 256, 0, stream>>>(W_r, W_z, W_h, Wbf);
    if (bf16path)
        conv_kernel<<<2 * STHALF_ / (8 * 256), 256, 0, stream>>>(state_in, state_out, st_bf);
    hist_kernel<<<TOTE_ / 256, 256, 0, stream>>>(A_rows, ptr);
    scan_kernel<<<SEGS_, 256, 0, stream>>>(ptr, cursor);
    fill_kernel<<<TOTE_ / 256, 256, 0, stream>>>(A_rows, A_vals, A_cols, cursor, vals_s, cols_s);
    if (bf16path)
        gather_bf_kernel<<<SEGS_ * N_ / 4, 256, 0, stream>>>(st_bf, vals_s, cols_s, ptr, abuf);
    else
        gather_f32_kernel<<<SEGS_ * N_ / 4, 256, 0, stream>>>(state_in, state_out,
                                                              vals_s, cols_s, ptr, abuf);
    gru_kernel<<<ROWS_ / 64, 256, 0, stream>>>(abuf, state_cur, Wbf,
                                               b_r, b_z, b_h, out);
}

// Round 4
// 188.962 us; speedup vs baseline: 2.2609x; 1.2416x over previous
//
#include <hip/hip_runtime.h>
#include <math.h>

// Problem constants
#define B_    8
#define N_    2000
#define ET_   2
#define L_    8
#define D_    64
#define NNZ_  32000
#define EN_   4000          // ET_*N_
#define LD_   512           // L_*D_
#define SEGS_ 16            // B_*ET_
#define SEGSTR_ 2001        // N_+1
#define TOTE_ 512000        // B_*ET_*NNZ_
#define ROWS_ 128000        // B_*N_*L_  (GEMM rows)
#define STHALF_ 16384000    // B_*EN_*LD_ elements per state tensor

typedef __attribute__((ext_vector_type(8))) short short8;
typedef __attribute__((ext_vector_type(4))) float f32x4;

// round-to-nearest-even f32 -> bf16 bits
__device__ __forceinline__ ushort bf(float x) {
    unsigned u = __float_as_uint(x);
    unsigned r = (u + 0x7FFFu + ((u >> 16) & 1u)) >> 16;
    return (ushort)r;
}

__device__ __forceinline__ float fast_tanh(float x) {
    float e = __expf(-2.f * fabsf(x));
    float t = (1.f - e) / (1.f + e);
    return (x < 0.f) ? -t : t;
}

// ---------------- state f32 -> bf16 conversion (streaming) ----------------
__global__ __launch_bounds__(256) void conv_kernel(const float* __restrict__ s_in,
                                                   const float* __restrict__ s_out,
                                                   ushort* __restrict__ st_bf) {
    int cid = blockIdx.x * 256 + threadIdx.x;          // < 4,096,000 chunks of 8
    size_t idx = (size_t)cid * 8;
    const float* src;
    if (idx < (size_t)STHALF_) src = s_in + idx;
    else                       src = s_out + (idx - STHALF_);
    float4 v0 = *(const float4*)src;
    float4 v1 = *(const float4*)(src + 4);
    union { ushort u[8]; uint4 v; } pk;
    pk.u[0] = bf(v0.x); pk.u[1] = bf(v0.y); pk.u[2] = bf(v0.z); pk.u[3] = bf(v0.w);
    pk.u[4] = bf(v1.x); pk.u[5] = bf(v1.y); pk.u[6] = bf(v1.z); pk.u[7] = bf(v1.w);
    *(uint4*)(st_bf + idx) = pk.v;
}

// ---------------- CSR build ----------------
__global__ void hist_kernel(const int* __restrict__ rows, int* __restrict__ ptr) {
    int idx = blockIdx.x * 256 + threadIdx.x;          // < TOTE_
    int seg = idx / NNZ_;                              // b*2+t  (A arrays are [B,2,NNZ])
    int row = rows[idx];
    atomicAdd(&ptr[seg * SEGSTR_ + row + 1], 1);
}

__global__ void scan_kernel(int* __restrict__ ptr, int* __restrict__ cursor) {
    int seg = blockIdx.x;                              // 16 blocks
    int* p = ptr + seg * SEGSTR_;
    int* c = cursor + seg * SEGSTR_;
    __shared__ int totals[256];
    int t = threadIdx.x;
    int v[8];
    int run = 0;
    int base = t * 8;
#pragma unroll
    for (int k = 0; k < 8; ++k) {
        int i = base + k;
        int x = (i < SEGSTR_) ? p[i] : 0;
        run += x;
        v[k] = run;
    }
    totals[t] = run;
    __syncthreads();
    if (t == 0) {
        int r = 0;
        for (int i = 0; i < 256; ++i) { int tmp = totals[i]; totals[i] = r; r += tmp; }
    }
    __syncthreads();
    int off = totals[t];
#pragma unroll
    for (int k = 0; k < 8; ++k) {
        int i = base + k;
        if (i < SEGSTR_) {
            int val = off + v[k];
            p[i] = val;
            c[i] = val;
        }
    }
}

// permute vals/cols directly into CSR order
__global__ void fill_kernel(const int* __restrict__ rows, const float* __restrict__ vals,
                            const int* __restrict__ cols, int* __restrict__ cursor,
                            float* __restrict__ vals_s, int* __restrict__ cols_s) {
    int idx = blockIdx.x * 256 + threadIdx.x;          // < TOTE_
    int seg = idx / NNZ_;
    int row = rows[idx];
    int pos = atomicAdd(&cursor[seg * SEGSTR_ + row], 1);
    vals_s[seg * NNZ_ + pos] = vals[idx];
    cols_s[seg * NNZ_ + pos] = cols[idx];
}

// ---------------- SpMM gather (bf16 states): one wave per (seg,row) ----------------
__global__ __launch_bounds__(256) void gather_bf_kernel(
    const ushort* __restrict__ st_bf, const float* __restrict__ vals_s,
    const int* __restrict__ cols_s, const int* __restrict__ ptr,
    ushort* __restrict__ abuf) {
    int xcd = blockIdx.x & 7;
    int s = blockIdx.x >> 3;                           // 0..999
    int half = (s >= 500) ? 1 : 0;
    int seg = xcd * 2 + half;
    int row = (s - half * 500) * 4 + (threadIdx.x >> 6);
    int lane = threadIdx.x & 63;
    int b = seg >> 1, t = seg & 1;
    const ushort* stp = st_bf + (size_t)t * STHALF_ + (size_t)b * (EN_ * LD_) + lane * 8;
    int s0 = ptr[seg * SEGSTR_ + row];
    int s1 = ptr[seg * SEGSTR_ + row + 1];
    int base = seg * NNZ_;
    float acc[8];
#pragma unroll
    for (int k = 0; k < 8; ++k) acc[k] = 0.f;
    for (int j = s0; j < s1; ++j) {
        float v = vals_s[base + j];
        int col = cols_s[base + j];
        uint4 x = *(const uint4*)(stp + (size_t)col * LD_);
        uint xs[4] = {x.x, x.y, x.z, x.w};
#pragma unroll
        for (int k = 0; k < 4; ++k) {
            float lo = __uint_as_float(xs[k] << 16);
            float hi = __uint_as_float(xs[k] & 0xFFFF0000u);
            acc[2 * k]     += v * lo;
            acc[2 * k + 1] += v * hi;
        }
    }
    union { ushort u[8]; uint4 v; } pk;
#pragma unroll
    for (int k = 0; k < 8; ++k) pk.u[k] = bf(acc[k]);
    ushort* dst = abuf + ((size_t)((t * B_ + b) * N_ + row)) * LD_ + lane * 8;
    *(uint4*)dst = pk.v;
}

// fallback (f32 states) if ws too small for bf16 copies
__global__ __launch_bounds__(256) void gather_f32_kernel(
    const float* __restrict__ state_in, const float* __restrict__ state_out,
    const float* __restrict__ vals_s, const int* __restrict__ cols_s,
    const int* __restrict__ ptr, ushort* __restrict__ abuf) {
    int xcd = blockIdx.x & 7;
    int s = blockIdx.x >> 3;
    int half = (s >= 500) ? 1 : 0;
    int seg = xcd * 2 + half;
    int row = (s - half * 500) * 4 + (threadIdx.x >> 6);
    int lane = threadIdx.x & 63;
    int b = seg >> 1, t = seg & 1;
    const float* st = (t ? state_out : state_in) + (size_t)b * (EN_ * LD_) + lane * 8;
    int s0 = ptr[seg * SEGSTR_ + row];
    int s1 = ptr[seg * SEGSTR_ + row + 1];
    int base = seg * NNZ_;
    float4 a0 = make_float4(0.f, 0.f, 0.f, 0.f);
    float4 a1 = make_float4(0.f, 0.f, 0.f, 0.f);
    for (int j = s0; j < s1; ++j) {
        float v = vals_s[base + j];
        int col = cols_s[base + j];
        const float* src = st + (size_t)col * LD_;
        float4 x0 = *(const float4*)src;
        float4 x1 = *(const float4*)(src + 4);
        a0.x += v * x0.x; a0.y += v * x0.y; a0.z += v * x0.z; a0.w += v * x0.w;
        a1.x += v * x1.x; a1.y += v * x1.y; a1.z += v * x1.z; a1.w += v * x1.w;
    }
    union { ushort u[8]; uint4 v; } pk;
    pk.u[0] = bf(a0.x); pk.u[1] = bf(a0.y); pk.u[2] = bf(a0.z); pk.u[3] = bf(a0.w);
    pk.u[4] = bf(a1.x); pk.u[5] = bf(a1.y); pk.u[6] = bf(a1.z); pk.u[7] = bf(a1.w);
    ushort* dst = abuf + ((size_t)((t * B_ + b) * N_ + row)) * LD_ + lane * 8;
    *(uint4*)dst = pk.v;
}

// ---------------- weight prep: f32 [64,192]x3 -> bf16 [192,192] ----------------
__global__ void wprep_kernel(const float* __restrict__ Wr, const float* __restrict__ Wz,
                             const float* __restrict__ Wh, ushort* __restrict__ Wbf) {
    int cid = blockIdx.x * 256 + threadIdx.x;          // < 4608 chunks of 8
    if (cid >= 4608) return;
    int row = cid / 24, c0 = (cid % 24) * 8;
    const float* src = (row < 64) ? (Wr + row * 192)
                     : (row < 128) ? (Wz + (row - 64) * 192)
                                   : (Wh + (row - 128) * 192);
    float4 v0 = *(const float4*)(src + c0);
    float4 v1 = *(const float4*)(src + c0 + 4);
    union { ushort u[8]; uint4 v; } pk;
    pk.u[0] = bf(v0.x); pk.u[1] = bf(v0.y); pk.u[2] = bf(v0.z); pk.u[3] = bf(v0.w);
    pk.u[4] = bf(v1.x); pk.u[5] = bf(v1.y); pk.u[6] = bf(v1.z); pk.u[7] = bf(v1.w);
    *(uint4*)(Wbf + row * 192 + c0) = pk.v;
}

// ---------------- GRU via MFMA bf16, 3-phase LDS-staged weights ----------------
// Block: 256 thr = 4 waves, 64 GEMM rows; wave owns 16 rows (one 16-row MFMA tile).
// Phase r/z/h: stage 64x192 bf16 weight panel into wsh, 24 MFMAs per wave per phase.
// A-frags live in registers, loaded straight from global (each element read once).
// r*cur crosses lanes through rcur LDS. Frag k-mapping: same permutation for A and B.
// C/D: col=lane&15, row=(lane>>4)*4+reg.
__global__ __launch_bounds__(256) void gru_kernel(
    const ushort* __restrict__ abuf, const float* __restrict__ state_cur,
    const ushort* __restrict__ Wbf,
    const float* __restrict__ br, const float* __restrict__ bz, const float* __restrict__ bh,
    float* __restrict__ out) {
    __shared__ ushort wsh[64][200];   // one 64-row weight panel (r, then z, then h)
    __shared__ ushort rcur[64][72];   // r * state_cur exchange, bf16
    int tid = threadIdx.x;
    int wave = tid >> 6, lane = tid & 63;
    int R0 = blockIdx.x * 64;
    int g = lane >> 4;                 // k-group 0..3
    int oc = lane & 15;                // output col within tile / A row within tile
    int arow = wave * 16 + oc;
    int rbase = wave * 16 + g * 4;     // C/D row for reg q: rbase+q

    // ---- stage r-panel (Wbf rows 0-63) ----
    {
        const uint4* srcw = (const uint4*)(Wbf);
#pragma unroll
        for (int j = 0; j < 6; ++j) {
            int i = tid + j * 256;             // < 1536
            int row = i / 24, c4 = i - row * 24;
            *(uint4*)&wsh[row][c4 * 8] = srcw[i];
        }
    }

    // ---- A-frags from global (issued during W staging) ----
    short8 afr[6];
    {
        const ushort* pin  = abuf + (size_t)(R0 + arow) * 64 + g * 8;
        const ushort* pout = pin + (size_t)ROWS_ * 64;
        afr[0] = *(const short8*)(pin);
        afr[1] = *(const short8*)(pin + 32);
        afr[2] = *(const short8*)(pout);
        afr[3] = *(const short8*)(pout + 32);
        const float* pc = state_cur + (size_t)(R0 + arow) * 64 + g * 8;
        float4 u0 = *(const float4*)(pc);
        float4 u1 = *(const float4*)(pc + 4);
        float4 u2 = *(const float4*)(pc + 32);
        float4 u3 = *(const float4*)(pc + 36);
        short8 t4, t5;
        t4[0] = (short)bf(u0.x); t4[1] = (short)bf(u0.y); t4[2] = (short)bf(u0.z); t4[3] = (short)bf(u0.w);
        t4[4] = (short)bf(u1.x); t4[5] = (short)bf(u1.y); t4[6] = (short)bf(u1.z); t4[7] = (short)bf(u1.w);
        t5[0] = (short)bf(u2.x); t5[1] = (short)bf(u2.y); t5[2] = (short)bf(u2.z); t5[3] = (short)bf(u2.w);
        t5[4] = (short)bf(u3.x); t5[5] = (short)bf(u3.y); t5[6] = (short)bf(u3.z); t5[7] = (short)bf(u3.w);
        afr[4] = t4; afr[5] = t5;
    }

    // cur values this lane will blend in the epilogues (f32 precision)
    float curv[4][4];
#pragma unroll
    for (int ct = 0; ct < 4; ++ct)
#pragma unroll
        for (int q = 0; q < 4; ++q)
            curv[ct][q] = state_cur[(size_t)(R0 + rbase + q) * 64 + ct * 16 + oc];

    __syncthreads();

    // ---- phase r: 4 col-tiles x 6 k-steps ----
    f32x4 accR[4];
#pragma unroll
    for (int ct = 0; ct < 4; ++ct) accR[ct] = (f32x4)(0.f);
#pragma unroll
    for (int ct = 0; ct < 4; ++ct) {
#pragma unroll
        for (int s = 0; s < 6; ++s) {
            short8 bfr = *(const short8*)&wsh[ct * 16 + oc][s * 32 + g * 8];
            accR[ct] = __builtin_amdgcn_mfma_f32_16x16x32_bf16(afr[s], bfr, accR[ct], 0, 0, 0);
        }
    }
    __syncthreads();                   // everyone done reading r-panel

    // ---- stage z-panel (rows 64-127), overlapped with r-gate epilogue ----
    {
        const uint4* srcw = (const uint4*)(Wbf + 64 * 192);
#pragma unroll
        for (int j = 0; j < 6; ++j) {
            int i = tid + j * 256;
            int row = i / 24, c4 = i - row * 24;
            *(uint4*)&wsh[row][c4 * 8] = srcw[i];
        }
    }
#pragma unroll
    for (int ct = 0; ct < 4; ++ct) {
        float brl = br[ct * 16 + oc];
#pragma unroll
        for (int q = 0; q < 4; ++q) {
            float rg = 1.f / (1.f + __expf(-(accR[ct][q] + brl)));
            rcur[rbase + q][ct * 16 + oc] = bf(rg * curv[ct][q]);
        }
    }
    __syncthreads();                   // z-panel staged AND rcur complete

    // ---- phase z ----
    f32x4 accZ[4];
#pragma unroll
    for (int ct = 0; ct < 4; ++ct) accZ[ct] = (f32x4)(0.f);
#pragma unroll
    for (int ct = 0; ct < 4; ++ct) {
#pragma unroll
        for (int s = 0; s < 6; ++s) {
            short8 bfr = *(const short8*)&wsh[ct * 16 + oc][s * 32 + g * 8];
            accZ[ct] = __builtin_amdgcn_mfma_f32_16x16x32_bf16(afr[s], bfr, accZ[ct], 0, 0, 0);
        }
    }
    __syncthreads();                   // everyone done reading z-panel

    // ---- stage h-panel (rows 128-191) ----
    {
        const uint4* srcw = (const uint4*)(Wbf + 128 * 192);
#pragma unroll
        for (int j = 0; j < 6; ++j) {
            int i = tid + j * 256;
            int row = i / 24, c4 = i - row * 24;
            *(uint4*)&wsh[row][c4 * 8] = srcw[i];
        }
    }
    __syncthreads();

    // ---- phase h: k-blocks 4,5 come from rcur ----
    short8 afh4 = *(const short8*)&rcur[arow][g * 8];
    short8 afh5 = *(const short8*)&rcur[arow][32 + g * 8];
    f32x4 accH[4];
#pragma unroll
    for (int ct = 0; ct < 4; ++ct) accH[ct] = (f32x4)(0.f);
#pragma unroll
    for (int ct = 0; ct < 4; ++ct) {
#pragma unroll
        for (int s = 0; s < 6; ++s) {
            short8 bfr = *(const short8*)&wsh[ct * 16 + oc][s * 32 + g * 8];
            short8 a = (s < 4) ? afr[s] : (s == 4 ? afh4 : afh5);
            accH[ct] = __builtin_amdgcn_mfma_f32_16x16x32_bf16(a, bfr, accH[ct], 0, 0, 0);
        }
    }

    // ---- final: out = (1-z)*cur + z*tanh(h) ----
#pragma unroll
    for (int ct = 0; ct < 4; ++ct) {
        float bzl = bz[ct * 16 + oc];
        float bhl = bh[ct * 16 + oc];
#pragma unroll
        for (int q = 0; q < 4; ++q) {
            float z = 1.f / (1.f + __expf(-(accZ[ct][q] + bzl)));
            float hh = fast_tanh(accH[ct][q] + bhl);
            out[(size_t)(R0 + rbase + q) * 64 + ct * 16 + oc] =
                (1.f - z) * curv[ct][q] + z * hh;
        }
    }
}

extern "C" void kernel_launch(void* const* d_in, const int* in_sizes, int n_in,
                              void* d_out, int out_size, void* d_ws, size_t ws_size,
                              hipStream_t stream) {
    const float* state_in  = (const float*)d_in[0];
    const float* state_out = (const float*)d_in[1];
    const float* state_cur = (const float*)d_in[2];
    const float* A_vals    = (const float*)d_in[3];
    const int*   A_rows    = (const int*)d_in[4];
    const int*   A_cols    = (const int*)d_in[5];
    const float* W_r = (const float*)d_in[6];
    const float* b_r = (const float*)d_in[7];
    const float* W_z = (const float*)d_in[8];
    const float* b_z = (const float*)d_in[9];
    const float* W_h = (const float*)d_in[10];
    const float* b_h = (const float*)d_in[11];
    float* out = (float*)d_out;

    // workspace layout
    char* p = (char*)d_ws;
    ushort* abuf = (ushort*)p;            p += (size_t)2 * ROWS_ * 64 * 2;   // 32,768,000 B
    ushort* Wbf  = (ushort*)p;            p += 36864 * 2;                    //     73,728 B
    int* ptr     = (int*)p;               p += 32016 * 4;                    //    128,064 B
    int* cursor  = (int*)p;               p += 32016 * 4;
    float* vals_s = (float*)p;            p += (size_t)SEGS_ * NNZ_ * 4;     //  2,048,000 B
    int* cols_s   = (int*)p;              p += (size_t)SEGS_ * NNZ_ * 4;
    ushort* st_bf = (ushort*)p;           p += (size_t)2 * STHALF_ * 2;      // 65,536,000 B
    bool bf16path = (size_t)(p - (char*)d_ws) <= ws_size;

    hipMemsetAsync(ptr, 0, 32016 * sizeof(int), stream);
    wprep_kernel<<<18, 256, 0, stream>>>(W_r, W_z, W_h, Wbf);
    if (bf16path)
        conv_kernel<<<2 * STHALF_ / (8 * 256), 256, 0, stream>>>(state_in, state_out, st_bf);
    hist_kernel<<<TOTE_ / 256, 256, 0, stream>>>(A_rows, ptr);
    scan_kernel<<<SEGS_, 256, 0, stream>>>(ptr, cursor);
    fill_kernel<<<TOTE_ / 256, 256, 0, stream>>>(A_rows, A_vals, A_cols, cursor, vals_s, cols_s);
    if (bf16path)
        gather_bf_kernel<<<SEGS_ * N_ / 4, 256, 0, stream>>>(st_bf, vals_s, cols_s, ptr, abuf);
    else
        gather_f32_kernel<<<SEGS_ * N_ / 4, 256, 0, stream>>>(state_in, state_out,
                                                              vals_s, cols_s, ptr, abuf);
    gru_kernel<<<ROWS_ / 64, 256, 0, stream>>>(abuf, state_cur, Wbf,
                                               b_r, b_z, b_h, out);
}

// Round 5
// 164.284 us; speedup vs baseline: 2.6005x; 1.1502x over previous
//
#include <hip/hip_runtime.h>
#include <math.h>

// Problem constants
#define B_    8
#define N_    2000
#define ET_   2
#define L_    8
#define D_    64
#define NNZ_  32000
#define EN_   4000          // ET_*N_
#define LD_   512           // L_*D_
#define SEGS_ 16            // B_*ET_
#define SEGSTR_ 2001        // N_+1
#define TOTE_ 512000        // B_*ET_*NNZ_
#define ROWS_ 128000        // B_*N_*L_  (GEMM rows)
#define STHALF_ 16384000    // B_*EN_*LD_ elements per state tensor

typedef __attribute__((ext_vector_type(8))) short short8;
typedef __attribute__((ext_vector_type(4))) float f32x4;

// round-to-nearest-even f32 -> bf16 bits
__device__ __forceinline__ ushort bf(float x) {
    unsigned u = __float_as_uint(x);
    unsigned r = (u + 0x7FFFu + ((u >> 16) & 1u)) >> 16;
    return (ushort)r;
}

__device__ __forceinline__ float fast_tanh(float x) {
    float e = __expf(-2.f * fabsf(x));
    float t = (1.f - e) / (1.f + e);
    return (x < 0.f) ? -t : t;
}

// ---------------- state f32 -> bf16 conversion (streaming) ----------------
__global__ __launch_bounds__(256) void conv_kernel(const float* __restrict__ s_in,
                                                   const float* __restrict__ s_out,
                                                   ushort* __restrict__ st_bf) {
    int cid = blockIdx.x * 256 + threadIdx.x;          // < 4,096,000 chunks of 8
    size_t idx = (size_t)cid * 8;
    const float* src;
    if (idx < (size_t)STHALF_) src = s_in + idx;
    else                       src = s_out + (idx - STHALF_);
    float4 v0 = *(const float4*)src;
    float4 v1 = *(const float4*)(src + 4);
    union { ushort u[8]; uint4 v; } pk;
    pk.u[0] = bf(v0.x); pk.u[1] = bf(v0.y); pk.u[2] = bf(v0.z); pk.u[3] = bf(v0.w);
    pk.u[4] = bf(v1.x); pk.u[5] = bf(v1.y); pk.u[6] = bf(v1.z); pk.u[7] = bf(v1.w);
    *(uint4*)(st_bf + idx) = pk.v;
}

// ---------------- CSR build ----------------
__global__ void hist_kernel(const int* __restrict__ rows, int* __restrict__ ptr) {
    int idx = blockIdx.x * 256 + threadIdx.x;          // < TOTE_
    int seg = idx / NNZ_;                              // b*2+t  (A arrays are [B,2,NNZ])
    int row = rows[idx];
    atomicAdd(&ptr[seg * SEGSTR_ + row + 1], 1);
}

__global__ void scan_kernel(int* __restrict__ ptr, int* __restrict__ cursor) {
    int seg = blockIdx.x;                              // 16 blocks
    int* p = ptr + seg * SEGSTR_;
    int* c = cursor + seg * SEGSTR_;
    __shared__ int totals[256];
    int t = threadIdx.x;
    int v[8];
    int run = 0;
    int base = t * 8;
#pragma unroll
    for (int k = 0; k < 8; ++k) {
        int i = base + k;
        int x = (i < SEGSTR_) ? p[i] : 0;
        run += x;
        v[k] = run;
    }
    totals[t] = run;
    __syncthreads();
    if (t == 0) {
        int r = 0;
        for (int i = 0; i < 256; ++i) { int tmp = totals[i]; totals[i] = r; r += tmp; }
    }
    __syncthreads();
    int off = totals[t];
#pragma unroll
    for (int k = 0; k < 8; ++k) {
        int i = base + k;
        if (i < SEGSTR_) {
            int val = off + v[k];
            p[i] = val;
            c[i] = val;
        }
    }
}

// permute (val,col) packed pairs directly into CSR order
__global__ void fill_kernel(const int* __restrict__ rows, const float* __restrict__ vals,
                            const int* __restrict__ cols, int* __restrict__ cursor,
                            uint2* __restrict__ ec_s) {
    int idx = blockIdx.x * 256 + threadIdx.x;          // < TOTE_
    int seg = idx / NNZ_;
    int row = rows[idx];
    int pos = atomicAdd(&cursor[seg * SEGSTR_ + row], 1);
    uint2 e;
    e.x = __float_as_uint(vals[idx]);
    e.y = (unsigned)cols[idx];
    ec_s[seg * NNZ_ + pos] = e;
}

// ---------------- SpMM gather (bf16 states): one wave per (seg,row) ----------------
// XCD-pinned (blockIdx.x & 7); edge loop unrolled x4 so 4 gathers are in flight.
__global__ __launch_bounds__(256) void gather_bf_kernel(
    const ushort* __restrict__ st_bf, const uint2* __restrict__ ec_s,
    const int* __restrict__ ptr, ushort* __restrict__ abuf) {
    int xcd = blockIdx.x & 7;
    int s = blockIdx.x >> 3;                           // 0..999
    int half = (s >= 500) ? 1 : 0;
    int seg = xcd * 2 + half;
    int row = (s - half * 500) * 4 + (threadIdx.x >> 6);
    int lane = threadIdx.x & 63;
    int b = seg >> 1, t = seg & 1;
    const ushort* stp = st_bf + (size_t)t * STHALF_ + (size_t)b * (EN_ * LD_) + lane * 8;
    int s0 = ptr[seg * SEGSTR_ + row];
    int s1 = ptr[seg * SEGSTR_ + row + 1];
    const uint2* ec = ec_s + seg * NNZ_;
    float acc[8];
#pragma unroll
    for (int k = 0; k < 8; ++k) acc[k] = 0.f;

    int j = s0;
    for (; j + 4 <= s1; j += 4) {
        uint2 e0 = ec[j];
        uint2 e1 = ec[j + 1];
        uint2 e2 = ec[j + 2];
        uint2 e3 = ec[j + 3];
        uint4 x0 = *(const uint4*)(stp + (size_t)e0.y * LD_);
        uint4 x1 = *(const uint4*)(stp + (size_t)e1.y * LD_);
        uint4 x2 = *(const uint4*)(stp + (size_t)e2.y * LD_);
        uint4 x3 = *(const uint4*)(stp + (size_t)e3.y * LD_);
        float v0 = __uint_as_float(e0.x), v1 = __uint_as_float(e1.x);
        float v2 = __uint_as_float(e2.x), v3 = __uint_as_float(e3.x);
        uint xs0[4] = {x0.x, x0.y, x0.z, x0.w};
        uint xs1[4] = {x1.x, x1.y, x1.z, x1.w};
        uint xs2[4] = {x2.x, x2.y, x2.z, x2.w};
        uint xs3[4] = {x3.x, x3.y, x3.z, x3.w};
#pragma unroll
        for (int k = 0; k < 4; ++k) {
            acc[2 * k]     += v0 * __uint_as_float(xs0[k] << 16);
            acc[2 * k + 1] += v0 * __uint_as_float(xs0[k] & 0xFFFF0000u);
            acc[2 * k]     += v1 * __uint_as_float(xs1[k] << 16);
            acc[2 * k + 1] += v1 * __uint_as_float(xs1[k] & 0xFFFF0000u);
            acc[2 * k]     += v2 * __uint_as_float(xs2[k] << 16);
            acc[2 * k + 1] += v2 * __uint_as_float(xs2[k] & 0xFFFF0000u);
            acc[2 * k]     += v3 * __uint_as_float(xs3[k] << 16);
            acc[2 * k + 1] += v3 * __uint_as_float(xs3[k] & 0xFFFF0000u);
        }
    }
    for (; j < s1; ++j) {
        uint2 e = ec[j];
        float v = __uint_as_float(e.x);
        uint4 x = *(const uint4*)(stp + (size_t)e.y * LD_);
        uint xs[4] = {x.x, x.y, x.z, x.w};
#pragma unroll
        for (int k = 0; k < 4; ++k) {
            acc[2 * k]     += v * __uint_as_float(xs[k] << 16);
            acc[2 * k + 1] += v * __uint_as_float(xs[k] & 0xFFFF0000u);
        }
    }

    union { ushort u[8]; uint4 v; } pk;
#pragma unroll
    for (int k = 0; k < 8; ++k) pk.u[k] = bf(acc[k]);
    ushort* dst = abuf + ((size_t)((t * B_ + b) * N_ + row)) * LD_ + lane * 8;
    *(uint4*)dst = pk.v;
}

// fallback (f32 states) if ws too small for bf16 copies
__global__ __launch_bounds__(256) void gather_f32_kernel(
    const float* __restrict__ state_in, const float* __restrict__ state_out,
    const uint2* __restrict__ ec_s, const int* __restrict__ ptr,
    ushort* __restrict__ abuf) {
    int xcd = blockIdx.x & 7;
    int s = blockIdx.x >> 3;
    int half = (s >= 500) ? 1 : 0;
    int seg = xcd * 2 + half;
    int row = (s - half * 500) * 4 + (threadIdx.x >> 6);
    int lane = threadIdx.x & 63;
    int b = seg >> 1, t = seg & 1;
    const float* st = (t ? state_out : state_in) + (size_t)b * (EN_ * LD_) + lane * 8;
    int s0 = ptr[seg * SEGSTR_ + row];
    int s1 = ptr[seg * SEGSTR_ + row + 1];
    const uint2* ec = ec_s + seg * NNZ_;
    float4 a0 = make_float4(0.f, 0.f, 0.f, 0.f);
    float4 a1 = make_float4(0.f, 0.f, 0.f, 0.f);
    for (int j = s0; j < s1; ++j) {
        uint2 e = ec[j];
        float v = __uint_as_float(e.x);
        const float* src = st + (size_t)e.y * LD_;
        float4 x0 = *(const float4*)src;
        float4 x1 = *(const float4*)(src + 4);
        a0.x += v * x0.x; a0.y += v * x0.y; a0.z += v * x0.z; a0.w += v * x0.w;
        a1.x += v * x1.x; a1.y += v * x1.y; a1.z += v * x1.z; a1.w += v * x1.w;
    }
    union { ushort u[8]; uint4 v; } pk;
    pk.u[0] = bf(a0.x); pk.u[1] = bf(a0.y); pk.u[2] = bf(a0.z); pk.u[3] = bf(a0.w);
    pk.u[4] = bf(a1.x); pk.u[5] = bf(a1.y); pk.u[6] = bf(a1.z); pk.u[7] = bf(a1.w);
    ushort* dst = abuf + ((size_t)((t * B_ + b) * N_ + row)) * LD_ + lane * 8;
    *(uint4*)dst = pk.v;
}

// ---------------- weight prep: f32 [64,192]x3 -> bf16 [192,192] ----------------
__global__ void wprep_kernel(const float* __restrict__ Wr, const float* __restrict__ Wz,
                             const float* __restrict__ Wh, ushort* __restrict__ Wbf) {
    int cid = blockIdx.x * 256 + threadIdx.x;          // < 4608 chunks of 8
    if (cid >= 4608) return;
    int row = cid / 24, c0 = (cid % 24) * 8;
    const float* src = (row < 64) ? (Wr + row * 192)
                     : (row < 128) ? (Wz + (row - 64) * 192)
                                   : (Wh + (row - 128) * 192);
    float4 v0 = *(const float4*)(src + c0);
    float4 v1 = *(const float4*)(src + c0 + 4);
    union { ushort u[8]; uint4 v; } pk;
    pk.u[0] = bf(v0.x); pk.u[1] = bf(v0.y); pk.u[2] = bf(v0.z); pk.u[3] = bf(v0.w);
    pk.u[4] = bf(v1.x); pk.u[5] = bf(v1.y); pk.u[6] = bf(v1.z); pk.u[7] = bf(v1.w);
    *(uint4*)(Wbf + row * 192 + c0) = pk.v;
}

// ---------------- GRU via MFMA bf16, 3-phase LDS-staged weights ----------------
__global__ __launch_bounds__(256) void gru_kernel(
    const ushort* __restrict__ abuf, const float* __restrict__ state_cur,
    const ushort* __restrict__ Wbf,
    const float* __restrict__ br, const float* __restrict__ bz, const float* __restrict__ bh,
    float* __restrict__ out) {
    __shared__ ushort wsh[64][200];   // one 64-row weight panel (r, then z, then h)
    __shared__ ushort rcur[64][72];   // r * state_cur exchange, bf16
    int tid = threadIdx.x;
    int wave = tid >> 6, lane = tid & 63;
    int R0 = blockIdx.x * 64;
    int g = lane >> 4;                 // k-group 0..3
    int oc = lane & 15;                // output col within tile / A row within tile
    int arow = wave * 16 + oc;
    int rbase = wave * 16 + g * 4;     // C/D row for reg q: rbase+q

    // ---- stage r-panel (Wbf rows 0-63) ----
    {
        const uint4* srcw = (const uint4*)(Wbf);
#pragma unroll
        for (int j = 0; j < 6; ++j) {
            int i = tid + j * 256;             // < 1536
            int row = i / 24, c4 = i - row * 24;
            *(uint4*)&wsh[row][c4 * 8] = srcw[i];
        }
    }

    // ---- A-frags from global (issued during W staging) ----
    short8 afr[6];
    {
        const ushort* pin  = abuf + (size_t)(R0 + arow) * 64 + g * 8;
        const ushort* pout = pin + (size_t)ROWS_ * 64;
        afr[0] = *(const short8*)(pin);
        afr[1] = *(const short8*)(pin + 32);
        afr[2] = *(const short8*)(pout);
        afr[3] = *(const short8*)(pout + 32);
        const float* pc = state_cur + (size_t)(R0 + arow) * 64 + g * 8;
        float4 u0 = *(const float4*)(pc);
        float4 u1 = *(const float4*)(pc + 4);
        float4 u2 = *(const float4*)(pc + 32);
        float4 u3 = *(const float4*)(pc + 36);
        short8 t4, t5;
        t4[0] = (short)bf(u0.x); t4[1] = (short)bf(u0.y); t4[2] = (short)bf(u0.z); t4[3] = (short)bf(u0.w);
        t4[4] = (short)bf(u1.x); t4[5] = (short)bf(u1.y); t4[6] = (short)bf(u1.z); t4[7] = (short)bf(u1.w);
        t5[0] = (short)bf(u2.x); t5[1] = (short)bf(u2.y); t5[2] = (short)bf(u2.z); t5[3] = (short)bf(u2.w);
        t5[4] = (short)bf(u3.x); t5[5] = (short)bf(u3.y); t5[6] = (short)bf(u3.z); t5[7] = (short)bf(u3.w);
        afr[4] = t4; afr[5] = t5;
    }

    // cur values this lane will blend in the epilogues (f32 precision)
    float curv[4][4];
#pragma unroll
    for (int ct = 0; ct < 4; ++ct)
#pragma unroll
        for (int q = 0; q < 4; ++q)
            curv[ct][q] = state_cur[(size_t)(R0 + rbase + q) * 64 + ct * 16 + oc];

    __syncthreads();

    // ---- phase r: 4 col-tiles x 6 k-steps ----
    f32x4 accR[4];
#pragma unroll
    for (int ct = 0; ct < 4; ++ct) accR[ct] = (f32x4)(0.f);
#pragma unroll
    for (int ct = 0; ct < 4; ++ct) {
#pragma unroll
        for (int s = 0; s < 6; ++s) {
            short8 bfr = *(const short8*)&wsh[ct * 16 + oc][s * 32 + g * 8];
            accR[ct] = __builtin_amdgcn_mfma_f32_16x16x32_bf16(afr[s], bfr, accR[ct], 0, 0, 0);
        }
    }
    __syncthreads();                   // everyone done reading r-panel

    // ---- stage z-panel (rows 64-127), overlapped with r-gate epilogue ----
    {
        const uint4* srcw = (const uint4*)(Wbf + 64 * 192);
#pragma unroll
        for (int j = 0; j < 6; ++j) {
            int i = tid + j * 256;
            int row = i / 24, c4 = i - row * 24;
            *(uint4*)&wsh[row][c4 * 8] = srcw[i];
        }
    }
#pragma unroll
    for (int ct = 0; ct < 4; ++ct) {
        float brl = br[ct * 16 + oc];
#pragma unroll
        for (int q = 0; q < 4; ++q) {
            float rg = 1.f / (1.f + __expf(-(accR[ct][q] + brl)));
            rcur[rbase + q][ct * 16 + oc] = bf(rg * curv[ct][q]);
        }
    }
    __syncthreads();                   // z-panel staged AND rcur complete

    // ---- phase z ----
    f32x4 accZ[4];
#pragma unroll
    for (int ct = 0; ct < 4; ++ct) accZ[ct] = (f32x4)(0.f);
#pragma unroll
    for (int ct = 0; ct < 4; ++ct) {
#pragma unroll
        for (int s = 0; s < 6; ++s) {
            short8 bfr = *(const short8*)&wsh[ct * 16 + oc][s * 32 + g * 8];
            accZ[ct] = __builtin_amdgcn_mfma_f32_16x16x32_bf16(afr[s], bfr, accZ[ct], 0, 0, 0);
        }
    }
    __syncthreads();                   // everyone done reading z-panel

    // ---- stage h-panel (rows 128-191) ----
    {
        const uint4* srcw = (const uint4*)(Wbf + 128 * 192);
#pragma unroll
        for (int j = 0; j < 6; ++j) {
            int i = tid + j * 256;
            int row = i / 24, c4 = i - row * 24;
            *(uint4*)&wsh[row][c4 * 8] = srcw[i];
        }
    }
    __syncthreads();

    // ---- phase h: k-blocks 4,5 come from rcur ----
    short8 afh4 = *(const short8*)&rcur[arow][g * 8];
    short8 afh5 = *(const short8*)&rcur[arow][32 + g * 8];
    f32x4 accH[4];
#pragma unroll
    for (int ct = 0; ct < 4; ++ct) accH[ct] = (f32x4)(0.f);
#pragma unroll
    for (int ct = 0; ct < 4; ++ct) {
#pragma unroll
        for (int s = 0; s < 6; ++s) {
            short8 bfr = *(const short8*)&wsh[ct * 16 + oc][s * 32 + g * 8];
            short8 a = (s < 4) ? afr[s] : (s == 4 ? afh4 : afh5);
            accH[ct] = __builtin_amdgcn_mfma_f32_16x16x32_bf16(a, bfr, accH[ct], 0, 0, 0);
        }
    }

    // ---- final: out = (1-z)*cur + z*tanh(h) ----
#pragma unroll
    for (int ct = 0; ct < 4; ++ct) {
        float bzl = bz[ct * 16 + oc];
        float bhl = bh[ct * 16 + oc];
#pragma unroll
        for (int q = 0; q < 4; ++q) {
            float z = 1.f / (1.f + __expf(-(accZ[ct][q] + bzl)));
            float hh = fast_tanh(accH[ct][q] + bhl);
            out[(size_t)(R0 + rbase + q) * 64 + ct * 16 + oc] =
                (1.f - z) * curv[ct][q] + z * hh;
        }
    }
}

extern "C" void kernel_launch(void* const* d_in, const int* in_sizes, int n_in,
                              void* d_out, int out_size, void* d_ws, size_t ws_size,
                              hipStream_t stream) {
    const float* state_in  = (const float*)d_in[0];
    const float* state_out = (const float*)d_in[1];
    const float* state_cur = (const float*)d_in[2];
    const float* A_vals    = (const float*)d_in[3];
    const int*   A_rows    = (const int*)d_in[4];
    const int*   A_cols    = (const int*)d_in[5];
    const float* W_r = (const float*)d_in[6];
    const float* b_r = (const float*)d_in[7];
    const float* W_z = (const float*)d_in[8];
    const float* b_z = (const float*)d_in[9];
    const float* W_h = (const float*)d_in[10];
    const float* b_h = (const float*)d_in[11];
    float* out = (float*)d_out;

    // workspace layout
    char* p = (char*)d_ws;
    ushort* abuf = (ushort*)p;            p += (size_t)2 * ROWS_ * 64 * 2;   // 32,768,000 B
    ushort* Wbf  = (ushort*)p;            p += 36864 * 2;                    //     73,728 B
    int* ptr     = (int*)p;               p += 32016 * 4;                    //    128,064 B
    int* cursor  = (int*)p;               p += 32016 * 4;
    uint2* ec_s  = (uint2*)p;             p += (size_t)SEGS_ * NNZ_ * 8;     //  4,096,000 B
    ushort* st_bf = (ushort*)p;           p += (size_t)2 * STHALF_ * 2;      // 65,536,000 B
    bool bf16path = (size_t)(p - (char*)d_ws) <= ws_size;

    hipMemsetAsync(ptr, 0, 32016 * sizeof(int), stream);
    wprep_kernel<<<18, 256, 0, stream>>>(W_r, W_z, W_h, Wbf);
    if (bf16path)
        conv_kernel<<<2 * STHALF_ / (8 * 256), 256, 0, stream>>>(state_in, state_out, st_bf);
    hist_kernel<<<TOTE_ / 256, 256, 0, stream>>>(A_rows, ptr);
    scan_kernel<<<SEGS_, 256, 0, stream>>>(ptr, cursor);
    fill_kernel<<<TOTE_ / 256, 256, 0, stream>>>(A_rows, A_vals, A_cols, cursor, ec_s);
    if (bf16path)
        gather_bf_kernel<<<SEGS_ * N_ / 4, 256, 0, stream>>>(st_bf, ec_s, ptr, abuf);
    else
        gather_f32_kernel<<<SEGS_ * N_ / 4, 256, 0, stream>>>(state_in, state_out,
                                                              ec_s, ptr, abuf);
    gru_kernel<<<ROWS_ / 64, 256, 0, stream>>>(abuf, state_cur, Wbf,
                                               b_r, b_z, b_h, out);
}